// Round 1
// baseline (76.895 us; speedup 1.0000x reference)
//
#include <hip/hip_runtime.h>

// Problem constants (reference: B=64, T=4096, H=512)
#define T_LEN 4096
#define H_LEN 512
#define B_LEN 64

// Closed form of the diagonal linear scan:
//   h_T[j] = sum_{t=0..T-1} a_j^{T-1-t} (b_j x_t + c_j)
//   z[bi]  = sum_t x[bi,t]*g[t] + K
//   g[t]   = sum_j w_j b_j a_j^{T-1-t}
//   K      = sum_j w_j c_j (1-a_j^T)/(1-a_j) + e
//
// Kernel 1: blocks 0..15 build g[t] (one t per thread, loop over j with
// exp2f(k*log2(a_j))); block 16 computes K in fp64 (geometric sum has up to
// 1000x amplification from 1/(1-a), so use doubles there — it's 512 terms).
__global__ void build_g_kernel(const float* __restrict__ a,
                               const float* __restrict__ b,
                               const float* __restrict__ c,
                               const float* __restrict__ w,
                               const float* __restrict__ e,
                               float* __restrict__ g,   // [T_LEN]
                               float* __restrict__ Kc)  // [1]
{
    const int tid = threadIdx.x;
    if (blockIdx.x < T_LEN / 256) {
        __shared__ float wb[H_LEN];
        __shared__ float l2a[H_LEN];
        for (int j = tid; j < H_LEN; j += blockDim.x) {
            wb[j]  = w[j] * b[j];
            l2a[j] = log2f(a[j]);
        }
        __syncthreads();
        const int   t = blockIdx.x * 256 + tid;
        const float k = (float)(T_LEN - 1 - t);
        float s = 0.f;
#pragma unroll 8
        for (int j = 0; j < H_LEN; ++j) {
            s += wb[j] * exp2f(k * l2a[j]);
        }
        g[t] = s;
    } else {
        // K block — fp64 for the geometric series.
        __shared__ double red[256];
        double s = 0.0;
        for (int j = tid; j < H_LEN; j += blockDim.x) {
            const double aj  = (double)a[j];
            const double geo = (1.0 - pow(aj, (double)T_LEN)) / (1.0 - aj);
            s += (double)w[j] * (double)c[j] * geo;
        }
        red[tid] = s;
        __syncthreads();
        for (int off = 128; off > 0; off >>= 1) {
            if (tid < off) red[tid] += red[tid + off];
            __syncthreads();
        }
        if (tid == 0) Kc[0] = (float)(red[0] + (double)e[0]);
    }
}

// Kernel 2: one block per batch row, float4 dot of x-row with g, wave64
// shuffle reduce, + K.
__global__ void dot_kernel(const float* __restrict__ x,  // [B_LEN, T_LEN]
                           const float* __restrict__ g,  // [T_LEN]
                           const float* __restrict__ Kc, // [1]
                           float* __restrict__ z)        // [B_LEN]
{
    const int row = blockIdx.x;
    const int tid = threadIdx.x;
    const float4* __restrict__ xr = (const float4*)(x + (size_t)row * T_LEN);
    const float4* __restrict__ gv = (const float4*)g;
    float s = 0.f;
    for (int i = tid; i < T_LEN / 4; i += blockDim.x) {
        const float4 xv = xr[i];
        const float4 gg = gv[i];
        s += xv.x * gg.x + xv.y * gg.y + xv.z * gg.z + xv.w * gg.w;
    }
    // wave64 butterfly reduce
#pragma unroll
    for (int off = 32; off > 0; off >>= 1)
        s += __shfl_down(s, off, 64);
    __shared__ float wsum[4];
    const int wave = tid >> 6;
    if ((tid & 63) == 0) wsum[wave] = s;
    __syncthreads();
    if (tid == 0) {
        z[row] = wsum[0] + wsum[1] + wsum[2] + wsum[3] + Kc[0];
    }
}

extern "C" void kernel_launch(void* const* d_in, const int* in_sizes, int n_in,
                              void* d_out, int out_size, void* d_ws, size_t ws_size,
                              hipStream_t stream) {
    const float* x = (const float*)d_in[0];  // [B,T]
    const float* a = (const float*)d_in[1];  // [H]
    const float* b = (const float*)d_in[2];  // [H]
    const float* c = (const float*)d_in[3];  // [H]
    const float* w = (const float*)d_in[4];  // [H]
    const float* e = (const float*)d_in[5];  // [1]
    float* out = (float*)d_out;              // [B] fp32

    float* g  = (float*)d_ws;                // T_LEN floats
    float* Kc = g + T_LEN;                   // 1 float

    build_g_kernel<<<T_LEN / 256 + 1, 256, 0, stream>>>(a, b, c, w, e, g, Kc);
    dot_kernel<<<B_LEN, 256, 0, stream>>>(x, g, Kc, out);
}

// Round 2
// 68.206 us; speedup vs baseline: 1.1274x; 1.1274x over previous
//
#include <hip/hip_runtime.h>

// Problem constants (reference: B=64, T=4096, H=512)
#define T_LEN 4096
#define H_LEN 512
#define B_LEN 64

// Closed form of the diagonal linear scan:
//   z[bi] = sum_t x[bi,t]*g[t] + K
//   g[t]  = sum_j w_j b_j a_j^{T-1-t}
//   K     = sum_j w_j c_j (1-a_j^T)/(1-a_j) + e
//
// Kernel 1 tiling: 64 blocks own 64-wide t-chunks; within a block, 4 threads
// per t each cover 128 j's (tid&63 = t-within-chunk, tid>>6 = j-quadrant).
// All inner-loop LDS reads are wave-uniform broadcasts (a wave is exactly one
// j-quadrant; every lane reads the same wb[j]/l2a[j]) -> no bank conflicts.
// Block 64 computes K in fp64 (1/(1-a) amplifies up to 1000x; 512 terms).
__global__ void build_g_kernel(const float* __restrict__ a,
                               const float* __restrict__ b,
                               const float* __restrict__ c,
                               const float* __restrict__ w,
                               const float* __restrict__ e,
                               float* __restrict__ g,   // [T_LEN]
                               float* __restrict__ Kc)  // [1]
{
    const int tid = threadIdx.x;
    if (blockIdx.x < T_LEN / 64) {
        __shared__ float wb[H_LEN];
        __shared__ float l2a[H_LEN];
        for (int j = tid; j < H_LEN; j += 256) {
            wb[j]  = w[j] * b[j];
            l2a[j] = log2f(a[j]);
        }
        __syncthreads();
        const int   tt = tid & 63;      // t within chunk
        const int   jq = tid >> 6;      // j quadrant (== wave id)
        const int   t  = blockIdx.x * 64 + tt;
        const float k  = (float)(T_LEN - 1 - t);
        const int   j0 = jq * (H_LEN / 4);
        float s = 0.f;
#pragma unroll 8
        for (int jj = 0; jj < H_LEN / 4; ++jj) {
            const int j = j0 + jj;
            s += wb[j] * exp2f(k * l2a[j]);
        }
        __shared__ float part[4][64];
        part[jq][tt] = s;
        __syncthreads();
        if (tid < 64) {
            g[blockIdx.x * 64 + tid] =
                part[0][tid] + part[1][tid] + part[2][tid] + part[3][tid];
        }
    } else {
        // K block — fp64 for the geometric series.
        __shared__ double red[256];
        double s = 0.0;
        for (int j = tid; j < H_LEN; j += 256) {
            const double aj  = (double)a[j];
            const double geo = (1.0 - pow(aj, (double)T_LEN)) / (1.0 - aj);
            s += (double)w[j] * (double)c[j] * geo;
        }
        red[tid] = s;
        __syncthreads();
        for (int off = 128; off > 0; off >>= 1) {
            if (tid < off) red[tid] += red[tid + off];
            __syncthreads();
        }
        if (tid == 0) Kc[0] = (float)(red[0] + (double)e[0]);
    }
}

// Kernel 2: one block per batch row, float4 dot of x-row with g, wave64
// shuffle reduce, + K.
__global__ void dot_kernel(const float* __restrict__ x,  // [B_LEN, T_LEN]
                           const float* __restrict__ g,  // [T_LEN]
                           const float* __restrict__ Kc, // [1]
                           float* __restrict__ z)        // [B_LEN]
{
    const int row = blockIdx.x;
    const int tid = threadIdx.x;
    const float4* __restrict__ xr = (const float4*)(x + (size_t)row * T_LEN);
    const float4* __restrict__ gv = (const float4*)g;
    float s = 0.f;
#pragma unroll
    for (int i = tid; i < T_LEN / 4; i += 256) {
        const float4 xv = xr[i];
        const float4 gg = gv[i];
        s += xv.x * gg.x + xv.y * gg.y + xv.z * gg.z + xv.w * gg.w;
    }
    // wave64 butterfly reduce
#pragma unroll
    for (int off = 32; off > 0; off >>= 1)
        s += __shfl_down(s, off, 64);
    __shared__ float wsum[4];
    const int wave = tid >> 6;
    if ((tid & 63) == 0) wsum[wave] = s;
    __syncthreads();
    if (tid == 0) {
        z[row] = wsum[0] + wsum[1] + wsum[2] + wsum[3] + Kc[0];
    }
}

extern "C" void kernel_launch(void* const* d_in, const int* in_sizes, int n_in,
                              void* d_out, int out_size, void* d_ws, size_t ws_size,
                              hipStream_t stream) {
    const float* x = (const float*)d_in[0];  // [B,T]
    const float* a = (const float*)d_in[1];  // [H]
    const float* b = (const float*)d_in[2];  // [H]
    const float* c = (const float*)d_in[3];  // [H]
    const float* w = (const float*)d_in[4];  // [H]
    const float* e = (const float*)d_in[5];  // [1]
    float* out = (float*)d_out;              // [B] fp32

    float* g  = (float*)d_ws;                // T_LEN floats
    float* Kc = g + T_LEN;                   // 1 float

    build_g_kernel<<<T_LEN / 64 + 1, 256, 0, stream>>>(a, b, c, w, e, g, Kc);
    dot_kernel<<<B_LEN, 256, 0, stream>>>(x, g, Kc, out);
}